// Round 6
// baseline (120.384 us; speedup 1.0000x reference)
//
#include <hip/hip_runtime.h>

typedef unsigned short ushort_t;
typedef __attribute__((ext_vector_type(8))) short short8;
typedef __attribute__((ext_vector_type(4))) float float4v;
typedef __attribute__((ext_vector_type(2))) float float2v;

#define Bn 32
#define Nn 2048
#define Cn 8
#define Fn 128
#define On 128
#define Kn 384   // 3*F
#define MT 64    // rows per workgroup (keeps B-stream amortized 4x vs MT=16)
#define LDSK 392 // Kn + 8 pad (shorts); row stride 784 B
#define NBLK ((Bn * Nn) / MT)  // 1024 blocks

// float -> bf16 bits, round-to-nearest-even (prep kernel only)
__device__ __forceinline__ ushort_t f2bf(float x) {
  unsigned u = __float_as_uint(x);
  u += 0x7fffu + ((u >> 16) & 1u);
  return (ushort_t)(u >> 16);
}

// HW packed f32->bf16 (RNE), 2 elements / instr.
__device__ __forceinline__ unsigned cvt_pk_bf16(float lo, float hi) {
  unsigned r;
  asm("v_cvt_pk_bf16_f32 %0, %1, %2" : "=v"(r) : "v"(lo), "v"(hi));
  return r;
}

// Pack concat(w_t, w_r, w_l) directly in MFMA B-fragment order (unchanged).
__global__ void prep_w_kernel(const float* __restrict__ w_t,
                              const float* __restrict__ w_l,
                              const float* __restrict__ w_r,
                              ushort_t* __restrict__ wsw) {
  int t = blockIdx.x * blockDim.x + threadIdx.x; // one short8 per thread
  if (t >= 6144) return;                         // 6144*8 = 49152 elements
  int lane = t & 63;
  int r = t >> 6;        // 0..95
  int ks = r % 12;
  int q = r / 12;        // 0..7
  int col = q * 16 + (lane & 15);
  int kbase = ((lane >> 4) * 8) + ks * 32;
  ushort_t* dst = wsw + (size_t)t * 8;
#pragma unroll
  for (int j = 0; j < 8; ++j) {
    int k = kbase + j;
    const float* src = (k < Fn) ? w_t : (k < 2 * Fn) ? w_r : w_l;
    int f = k & (Fn - 1);
    dst[j] = f2bf(src[f * On + col]);
  }
}

// Issue the 9 gather loads (self + 8 children) for global row g.
// 64-lane group: each lane owns floats [ln*2, ln*2+2) -> float2 loads,
// 64 x 8 B = 512 B per instr, fully coalesced.
__device__ __forceinline__ void issue_row2(const float* __restrict__ nodes,
                                           int g, int ln,
                                           const int4& a, const int4& b,
                                           float2v (&dst)[9]) {
  const int base_row = g & ~(Nn - 1);  // b * Nn
  const float2v* np = (const float2v*)nodes;
  dst[0] = np[(size_t)g * (Fn / 2) + ln];  // self
  const int id[Cn] = {a.x, a.y, a.z, a.w, b.x, b.y, b.z, b.w};
#pragma unroll
  for (int c = 0; c < Cn; ++c) {
    // fault-proofing clamp: a replay with poisoned `children` cannot fault.
    const int ix = id[c] & (Nn - 1);
    dst[1 + c] = np[(size_t)(base_row + ix) * (Fn / 2) + ln];
  }
}

// Consume one row's buffered vectors: coefficients, rr, ll = msum - rr,
// pack to bf16 (HW cvt_pk), write LDS agg row.
__device__ __forceinline__ void compute_row2(ushort_t* __restrict__ agg,
                                             int row, int ln,
                                             const int4& a, const int4& b,
                                             const float2v (&v)[9]) {
  const int id[Cn] = {a.x, a.y, a.z, a.w, b.x, b.y, b.z, b.w};
  int ns = 0;
#pragma unroll
  for (int c = 0; c < Cn; ++c) ns += (id[c] != 0) ? 1 : 0;
  const bool single = (ns == 1);
  const float rden = (ns > 1) ? (1.0f / (float)(ns - 1)) : 0.0f;

  float2v rr = {0.f, 0.f};
  float2v ms = {0.f, 0.f};
#pragma unroll
  for (int c = 0; c < Cn; ++c) {
    const float m = (id[c] != 0) ? 1.0f : 0.0f;
    float cr = single ? ((c == 0) ? 0.5f : 0.0f) : ((float)c * rden);
    cr *= m;
    const float2v vc = v[1 + c];
    rr += cr * vc;
    ms += m * vc;  // masked plain sum
  }
  const float2v ll = ms - rr;  // c_l = (1 - c_r) * mask

  ushort_t* arow = agg + row * LDSK + ln * 2;
  *(unsigned*)(arow)          = cvt_pk_bf16(v[0].x, v[0].y);
  *(unsigned*)(arow + Fn)     = cvt_pk_bf16(rr.x, rr.y);
  *(unsigned*)(arow + 2 * Fn) = cvt_pk_bf16(ll.x, ll.y);
}

// 512 threads, 8 waves. Lean-by-construction body (~80 VGPR natural):
// float2 gather buffers (36), 3-pair children rotation, rolling 2x2
// A-fragment buffer + bf[12] in Phase B.
// launch_bounds(512,5): VGPR budget 102 (safe slack for RA — the forced-85
// budget of (512,6) is the prime suspect for the R4/R5 container deaths).
// If the allocator naturally lands <=85 VGPR we still get 3 blocks/CU
// (24 waves, LDS 3x49=147<=160); occupancy follows ACTUAL VGPR, not the cap.
__global__ __launch_bounds__(512, 5)
void tree_conv_kernel(const float* __restrict__ nodes,
                      const int* __restrict__ children,
                      const ushort_t* __restrict__ wsw,
                      const float* __restrict__ bias,
                      float* __restrict__ out) {
  __shared__ __align__(16) ushort_t agg[MT * LDSK];  // 64 x 784 B = 49 KiB

  const int tid = threadIdx.x;

  // XCD-locality swizzle (grid 1024): XCD k owns batches 4k..4k+3
  // (4 MB of nodes -> fits the XCD's 4 MiB L2).
  const int sb = ((blockIdx.x & 7) << 7) | (blockIdx.x >> 3);

  const int wv = tid >> 6;  // wave id 0..7 (wave-uniform by construction)
  const int ln = tid & 63;

  // ---------------- Phase A: 2-deep register-pipelined gather ---------------
  // wave wv owns rows wv*8 .. wv*8+7; lane owns floats [ln*2, ln*2+2).
  {
    const int g0 = sb * MT + wv * 8;

    int4 pa0, pb0, pa1, pb1, pa2, pb2;  // 3-pair rotation
#define LDCH(A, B, i)                                                        \
  {                                                                          \
    const int4* p4 = (const int4*)(children + (size_t)(g0 + (i)) * Cn);      \
    A = p4[0];                                                               \
    B = p4[1];                                                               \
  }
    LDCH(pa0, pb0, 0) LDCH(pa1, pb1, 1) LDCH(pa2, pb2, 2)

    float2v v0[9], v1[9];
    issue_row2(nodes, g0 + 0, ln, pa0, pb0, v0);
    issue_row2(nodes, g0 + 1, ln, pa1, pb1, v1);

    compute_row2(agg, wv * 8 + 0, ln, pa0, pb0, v0);
    LDCH(pa0, pb0, 3)
    issue_row2(nodes, g0 + 2, ln, pa2, pb2, v0);

    compute_row2(agg, wv * 8 + 1, ln, pa1, pb1, v1);
    LDCH(pa1, pb1, 4)
    issue_row2(nodes, g0 + 3, ln, pa0, pb0, v1);  // ch3

    compute_row2(agg, wv * 8 + 2, ln, pa2, pb2, v0);
    LDCH(pa2, pb2, 5)
    issue_row2(nodes, g0 + 4, ln, pa1, pb1, v0);  // ch4

    compute_row2(agg, wv * 8 + 3, ln, pa0, pb0, v1);
    LDCH(pa0, pb0, 6)
    issue_row2(nodes, g0 + 5, ln, pa2, pb2, v1);  // ch5

    compute_row2(agg, wv * 8 + 4, ln, pa1, pb1, v0);
    LDCH(pa1, pb1, 7)
    issue_row2(nodes, g0 + 6, ln, pa0, pb0, v0);  // ch6

    compute_row2(agg, wv * 8 + 5, ln, pa2, pb2, v1);
    issue_row2(nodes, g0 + 7, ln, pa1, pb1, v1);  // ch7

    compute_row2(agg, wv * 8 + 6, ln, pa0, pb0, v0);
    compute_row2(agg, wv * 8 + 7, ln, pa1, pb1, v1);
#undef LDCH
  }

  // ---------------- Phase B: MFMA; wave wv owns col-tile wv ----------------
  const int ct = wv;
  const int l15 = ln & 15;
  const int quad = ln >> 4;

  // B loads issue before the barrier (latency overlapped with Phase A tail).
  short8 bf[12];
  const short8* bbase = (const short8*)wsw + ln;
#pragma unroll
  for (int ks = 0; ks < 12; ++ks) bf[ks] = bbase[(ct * 12 + ks) * 64];
  const float bb = bias[ct * 16 + l15];

  // Standard barrier (drains all counters): the asm lgkmcnt-only barrier is
  // removed as a container-death suspect; cost is one vmcnt drain per block.
  __syncthreads();

#pragma unroll
  for (int mt = 0; mt < 4; ++mt) {
    const ushort_t* ar = agg + (mt * 16 + l15) * LDSK + quad * 8;
    // Rolling 2x2 A-fragment buffer (16 VGPR) instead of af[12] (48):
    // ds_read chunk c+1 issues while chunk c's MFMAs run.
    short8 a0 = *(const short8*)(ar + 0 * 32);
    short8 a1 = *(const short8*)(ar + 1 * 32);
    float4v acc = {0.f, 0.f, 0.f, 0.f};
    short8 c0 = *(const short8*)(ar + 2 * 32);
    short8 c1 = *(const short8*)(ar + 3 * 32);
    acc = __builtin_amdgcn_mfma_f32_16x16x32_bf16(a0, bf[0], acc, 0, 0, 0);
    acc = __builtin_amdgcn_mfma_f32_16x16x32_bf16(a1, bf[1], acc, 0, 0, 0);
    a0 = *(const short8*)(ar + 4 * 32);
    a1 = *(const short8*)(ar + 5 * 32);
    acc = __builtin_amdgcn_mfma_f32_16x16x32_bf16(c0, bf[2], acc, 0, 0, 0);
    acc = __builtin_amdgcn_mfma_f32_16x16x32_bf16(c1, bf[3], acc, 0, 0, 0);
    c0 = *(const short8*)(ar + 6 * 32);
    c1 = *(const short8*)(ar + 7 * 32);
    acc = __builtin_amdgcn_mfma_f32_16x16x32_bf16(a0, bf[4], acc, 0, 0, 0);
    acc = __builtin_amdgcn_mfma_f32_16x16x32_bf16(a1, bf[5], acc, 0, 0, 0);
    a0 = *(const short8*)(ar + 8 * 32);
    a1 = *(const short8*)(ar + 9 * 32);
    acc = __builtin_amdgcn_mfma_f32_16x16x32_bf16(c0, bf[6], acc, 0, 0, 0);
    acc = __builtin_amdgcn_mfma_f32_16x16x32_bf16(c1, bf[7], acc, 0, 0, 0);
    c0 = *(const short8*)(ar + 10 * 32);
    c1 = *(const short8*)(ar + 11 * 32);
    acc = __builtin_amdgcn_mfma_f32_16x16x32_bf16(a0, bf[8], acc, 0, 0, 0);
    acc = __builtin_amdgcn_mfma_f32_16x16x32_bf16(a1, bf[9], acc, 0, 0, 0);
    acc = __builtin_amdgcn_mfma_f32_16x16x32_bf16(c0, bf[10], acc, 0, 0, 0);
    acc = __builtin_amdgcn_mfma_f32_16x16x32_bf16(c1, bf[11], acc, 0, 0, 0);

    const int grow0 = sb * MT + mt * 16 + quad * 4;
#pragma unroll
    for (int r2 = 0; r2 < 4; ++r2) {
      out[(size_t)(grow0 + r2) * On + ct * 16 + l15] = fmaxf(acc[r2] + bb, 0.f);
    }
  }
}

extern "C" void kernel_launch(void* const* d_in, const int* in_sizes, int n_in,
                              void* d_out, int out_size, void* d_ws, size_t ws_size,
                              hipStream_t stream) {
  const float* nodes = (const float*)d_in[0];
  const int* children = (const int*)d_in[1];
  const float* w_t = (const float*)d_in[2];
  const float* w_l = (const float*)d_in[3];
  const float* w_r = (const float*)d_in[4];
  const float* bias = (const float*)d_in[5];
  float* out = (float*)d_out;
  ushort_t* wsw = (ushort_t*)d_ws;  // 49152 bf16 = 96 KiB, fragment-swizzled

  prep_w_kernel<<<24, 256, 0, stream>>>(w_t, w_l, w_r, wsw);
  tree_conv_kernel<<<NBLK, 512, 0, stream>>>(nodes, children, wsw, bias, out);
}

// Round 7
// 113.085 us; speedup vs baseline: 1.0645x; 1.0645x over previous
//
#include <hip/hip_runtime.h>

typedef unsigned short ushort_t;
typedef __attribute__((ext_vector_type(8))) short short8;
typedef __attribute__((ext_vector_type(4))) float float4v;
typedef __attribute__((ext_vector_type(2))) unsigned int uint2v;

#define Bn 32
#define Nn 2048
#define Cn 8
#define Fn 128
#define On 128
#define Kn 384    // 3*F
#define MTB 64    // rows per workgroup (B-stream amortization, as R2/R3)
#define TT 32     // rows per tile; 2 tiles per block, double-buffered LDS
#define LDSK 392  // Kn + 8 pad (shorts); row stride 784 B (16B-aligned)
#define NBLK ((Bn * Nn) / MTB)  // 1024 blocks

// float -> bf16 bits, round-to-nearest-even (prep kernel only)
__device__ __forceinline__ ushort_t f2bf(float x) {
  unsigned u = __float_as_uint(x);
  u += 0x7fffu + ((u >> 16) & 1u);
  return (ushort_t)(u >> 16);
}

// HW packed f32->bf16 (RNE), 2 elements / instr.
__device__ __forceinline__ unsigned cvt_pk_bf16(float lo, float hi) {
  unsigned r;
  asm("v_cvt_pk_bf16_f32 %0, %1, %2" : "=v"(r) : "v"(lo), "v"(hi));
  return r;
}

__device__ __forceinline__ uint2v pack4(float4v v) {
  uint2v r;
  r.x = cvt_pk_bf16(v.x, v.y);
  r.y = cvt_pk_bf16(v.z, v.w);
  return r;
}

// Pack concat(w_t, w_r, w_l) directly in MFMA B-fragment order (unchanged).
__global__ void prep_w_kernel(const float* __restrict__ w_t,
                              const float* __restrict__ w_l,
                              const float* __restrict__ w_r,
                              ushort_t* __restrict__ wsw) {
  int t = blockIdx.x * blockDim.x + threadIdx.x; // one short8 per thread
  if (t >= 6144) return;                         // 6144*8 = 49152 elements
  int lane = t & 63;
  int r = t >> 6;        // 0..95
  int ks = r % 12;
  int q = r / 12;        // 0..7
  int col = q * 16 + (lane & 15);
  int kbase = ((lane >> 4) * 8) + ks * 32;
  ushort_t* dst = wsw + (size_t)t * 8;
#pragma unroll
  for (int j = 0; j < 8; ++j) {
    int k = kbase + j;
    const float* src = (k < Fn) ? w_t : (k < 2 * Fn) ? w_r : w_l;
    int f = k & (Fn - 1);
    dst[j] = f2bf(src[f * On + col]);
  }
}

// Issue the 9 gather loads (self + 8 children) for global row g.
// 32-lane group, float4/lane: 32 x 16 B = 512 B per instr, fully coalesced.
__device__ __forceinline__ void issue_row(const float* __restrict__ nodes,
                                          int g, int l32,
                                          const int4& a, const int4& b,
                                          float4v (&dst)[9]) {
  const int base_row = g & ~(Nn - 1);  // b * Nn
  const float4v* np = (const float4v*)nodes;
  dst[0] = np[(size_t)g * (Fn / 4) + l32];  // self
  const int id[Cn] = {a.x, a.y, a.z, a.w, b.x, b.y, b.z, b.w};
#pragma unroll
  for (int c = 0; c < Cn; ++c) {
    // fault-proofing clamp: a replay with poisoned `children` cannot fault.
    const int ix = id[c] & (Nn - 1);
    dst[1 + c] = np[(size_t)(base_row + ix) * (Fn / 4) + l32];
  }
}

// Consume one row's buffered vectors: coefficients, rr, ll = msum - rr,
// pack to bf16 (HW cvt_pk), write one LDS agg row of the given tile buffer.
__device__ __forceinline__ void compute_row(ushort_t* __restrict__ aggT,
                                            int row, int l32,
                                            const int4& a, const int4& b,
                                            const float4v (&v)[9]) {
  const int id[Cn] = {a.x, a.y, a.z, a.w, b.x, b.y, b.z, b.w};
  int ns = 0;
#pragma unroll
  for (int c = 0; c < Cn; ++c) ns += (id[c] != 0) ? 1 : 0;
  const bool single = (ns == 1);
  const float rden = (ns > 1) ? (1.0f / (float)(ns - 1)) : 0.0f;

  float4v rr = {0.f, 0.f, 0.f, 0.f};
  float4v ms = {0.f, 0.f, 0.f, 0.f};
#pragma unroll
  for (int c = 0; c < Cn; ++c) {
    const float m = (id[c] != 0) ? 1.0f : 0.0f;
    float cr = single ? ((c == 0) ? 0.5f : 0.0f) : ((float)c * rden);
    cr *= m;
    const float4v vc = v[1 + c];
    rr += cr * vc;
    ms += m * vc;  // masked plain sum
  }
  const float4v ll = ms - rr;  // c_l = (1 - c_r) * mask

  ushort_t* arow = aggT + row * LDSK + l32 * 4;
  *(uint2v*)(arow)          = pack4(v[0]);
  *(uint2v*)(arow + Fn)     = pack4(rr);
  *(uint2v*)(arow + 2 * Fn) = pack4(ll);
}

// One 16-row M-tile x both of this wave's col-tiles: 12 ds_read_b128 (af
// shared across ct0/ct1) + 24 MFMA + 8 stores.
__device__ __forceinline__ void gemm_mt(const ushort_t* __restrict__ aggT,
                                        int mt, int l15, int quad,
                                        const short8 (&bf0)[12],
                                        const short8 (&bf1)[12],
                                        float bb0, float bb1, int ct0, int ct1,
                                        int growbase,
                                        float* __restrict__ out) {
  const ushort_t* ar = aggT + (mt * 16 + l15) * LDSK + quad * 8;
  short8 af[12];
#pragma unroll
  for (int ks = 0; ks < 12; ++ks) af[ks] = *(const short8*)(ar + ks * 32);

  float4v a0 = {0.f, 0.f, 0.f, 0.f};
  float4v a1 = {0.f, 0.f, 0.f, 0.f};
#pragma unroll
  for (int ks = 0; ks < 12; ++ks)
    a0 = __builtin_amdgcn_mfma_f32_16x16x32_bf16(af[ks], bf0[ks], a0, 0, 0, 0);
#pragma unroll
  for (int ks = 0; ks < 12; ++ks)
    a1 = __builtin_amdgcn_mfma_f32_16x16x32_bf16(af[ks], bf1[ks], a1, 0, 0, 0);

  const int grow0 = growbase + mt * 16 + quad * 4;
#pragma unroll
  for (int r2 = 0; r2 < 4; ++r2) {
    const size_t ro = (size_t)(grow0 + r2) * On;
    out[ro + ct0 * 16 + l15] = fmaxf(a0[r2] + bb0, 0.f);
    out[ro + ct1 * 16 + l15] = fmaxf(a1[r2] + bb1, 0.f);
  }
}

// 256 threads, 4 waves. Two-tile software pipeline:
//   A(T0) -> bar -> [B(T0) MFMA interleaved with A(T1) gathers] -> bar -> B(T1)
// launch_bounds(256,2): 256-VGPR budget — R1/R6 evidence says wins come from
// register depth, not wave count. Expected ~25% occupancy (8 waves/CU), by
// design. LDS 2 tiles x 24.5 KiB = 49 KiB -> 2 blocks/CU (VGPR-capped anyway).
__global__ __launch_bounds__(256, 2)
void tree_conv_kernel(const float* __restrict__ nodes,
                      const int* __restrict__ children,
                      const ushort_t* __restrict__ wsw,
                      const float* __restrict__ bias,
                      float* __restrict__ out) {
  __shared__ __align__(16) ushort_t agg[2][TT * LDSK];  // 2 x 24.5 KiB

  const int tid = threadIdx.x;

  // XCD-locality swizzle (grid 1024): XCD k owns batches 4k..4k+3
  // (4 MB of nodes -> fits the XCD's 4 MiB L2).
  const int sb = ((blockIdx.x & 7) << 7) | (blockIdx.x >> 3);
  const int gbase = sb * MTB;

  const int ln = tid & 63;
  const int wv = tid >> 6;   // 0..3
  const int grp = tid >> 5;  // 0..7 (A-phase 32-lane group)
  const int l32 = tid & 31;
  const int l15 = ln & 15;
  const int quad = ln >> 4;
  const int ct0 = wv * 2, ct1 = wv * 2 + 1;

  // --- bf preload FIRST: L2-hot, latency fully hidden under A(T0) ---------
  short8 bf0[12], bf1[12];
  const short8* bbase = (const short8*)wsw + ln;
#pragma unroll
  for (int ks = 0; ks < 12; ++ks) bf0[ks] = bbase[(ct0 * 12 + ks) * 64];
#pragma unroll
  for (int ks = 0; ks < 12; ++ks) bf1[ks] = bbase[(ct1 * 12 + ks) * 64];
  const float bb0 = bias[ct0 * 16 + l15];
  const float bb1 = bias[ct1 * 16 + l15];

  // --- A(T0): rows grp + it*8 of tile 0, 2-deep register pipeline ----------
  {
    const int g0 = gbase + grp;  // + it*8
    int4 ca[4], cb[4];
#pragma unroll
    for (int it = 0; it < 4; ++it) {
      const int4* p4 = (const int4*)(children + (size_t)(g0 + it * 8) * Cn);
      ca[it] = p4[0];
      cb[it] = p4[1];
    }
    float4v v0[9], v1[9];
    issue_row(nodes, g0 + 0 * 8, l32, ca[0], cb[0], v0);
    issue_row(nodes, g0 + 1 * 8, l32, ca[1], cb[1], v1);
    compute_row(agg[0], 0 * 8 + grp, l32, ca[0], cb[0], v0);
    issue_row(nodes, g0 + 2 * 8, l32, ca[2], cb[2], v0);
    compute_row(agg[0], 1 * 8 + grp, l32, ca[1], cb[1], v1);
    issue_row(nodes, g0 + 3 * 8, l32, ca[3], cb[3], v1);
    compute_row(agg[0], 2 * 8 + grp, l32, ca[2], cb[2], v0);
    compute_row(agg[0], 3 * 8 + grp, l32, ca[3], cb[3], v1);
  }

  __syncthreads();  // agg[0] complete

  // --- Interleave: B(T0) MFMA tiles with A(T1) gather rows -----------------
  {
    const int g1 = gbase + TT + grp;  // tile-1 rows: + it*8
    int4 ca[4], cb[4];
#pragma unroll
    for (int it = 0; it < 4; ++it) {
      const int4* p4 = (const int4*)(children + (size_t)(g1 + it * 8) * Cn);
      ca[it] = p4[0];
      cb[it] = p4[1];
    }
    float4v v[9];
    issue_row(nodes, g1 + 0 * 8, l32, ca[0], cb[0], v);  // T1r0 in flight...
    gemm_mt(agg[0], 0, l15, quad, bf0, bf1, bb0, bb1, ct0, ct1, gbase, out);
    compute_row(agg[1], 0 * 8 + grp, l32, ca[0], cb[0], v);
    issue_row(nodes, g1 + 1 * 8, l32, ca[1], cb[1], v);  // T1r1 in flight...
    gemm_mt(agg[0], 1, l15, quad, bf0, bf1, bb0, bb1, ct0, ct1, gbase, out);
    compute_row(agg[1], 1 * 8 + grp, l32, ca[1], cb[1], v);
    issue_row(nodes, g1 + 2 * 8, l32, ca[2], cb[2], v);  // tail rows: TLP-covered
    compute_row(agg[1], 2 * 8 + grp, l32, ca[2], cb[2], v);
    issue_row(nodes, g1 + 3 * 8, l32, ca[3], cb[3], v);
    compute_row(agg[1], 3 * 8 + grp, l32, ca[3], cb[3], v);
  }

  __syncthreads();  // agg[1] complete

  // --- B(T1) ---------------------------------------------------------------
  gemm_mt(agg[1], 0, l15, quad, bf0, bf1, bb0, bb1, ct0, ct1, gbase + TT, out);
  gemm_mt(agg[1], 1, l15, quad, bf0, bf1, bb0, bb1, ct0, ct1, gbase + TT, out);
}

extern "C" void kernel_launch(void* const* d_in, const int* in_sizes, int n_in,
                              void* d_out, int out_size, void* d_ws, size_t ws_size,
                              hipStream_t stream) {
  const float* nodes = (const float*)d_in[0];
  const int* children = (const int*)d_in[1];
  const float* w_t = (const float*)d_in[2];
  const float* w_l = (const float*)d_in[3];
  const float* w_r = (const float*)d_in[4];
  const float* bias = (const float*)d_in[5];
  float* out = (float*)d_out;
  ushort_t* wsw = (ushort_t*)d_ws;  // 49152 bf16 = 96 KiB, fragment-swizzled

  prep_w_kernel<<<24, 256, 0, stream>>>(w_t, w_l, w_r, wsw);
  tree_conv_kernel<<<NBLK, 256, 0, stream>>>(nodes, children, wsw, bias, out);
}